// Round 1
// baseline (714.144 us; speedup 1.0000x reference)
//
#include <hip/hip_runtime.h>
#include <hip/hip_bf16.h>

// Problem constants
#define BB   64
#define CIN  3
#define HH   224
#define WW   224
#define C1   32
#define H1   112
#define W1   112
#define C2   64
#define H2   56
#define W2   56
#define FEATN 64
#define OUTN 1024
#define K3TOT (FEATN*FEATN*FEATN)   // 262144

typedef __bf16 bf16x8 __attribute__((ext_vector_type(8)));
typedef float  f32x4  __attribute__((ext_vector_type(4)));

// ---------------- conv1: (64,3,224,224) -> relu -> (64,32,112,112), s=2 p=1 ----
__global__ __launch_bounds__(256) void conv1_kernel(const float* __restrict__ x,
        const float* __restrict__ w1, const float* __restrict__ b1,
        float* __restrict__ h1) {
    int pos = blockIdx.x * 256 + threadIdx.x;        // 64*112*112 = 802816
    int b   = pos / (H1 * W1);
    int rem = pos - b * (H1 * W1);
    int oy  = rem / W1;
    int ox  = rem - oy * W1;
    int iy0 = oy * 2 - 1, ix0 = ox * 2 - 1;

    float win[27];
    #pragma unroll
    for (int c = 0; c < CIN; ++c)
      #pragma unroll
      for (int dy = 0; dy < 3; ++dy)
        #pragma unroll
        for (int dx = 0; dx < 3; ++dx) {
          int iy = iy0 + dy, ix = ix0 + dx;
          bool ok = (iy >= 0) & (iy < HH) & (ix >= 0) & (ix < WW);
          win[c*9 + dy*3 + dx] = ok ? x[((b*CIN + c)*HH + iy)*WW + ix] : 0.f;
        }

    #pragma unroll 4
    for (int oc = 0; oc < C1; ++oc) {
      float acc = b1[oc];
      #pragma unroll
      for (int q = 0; q < 27; ++q)
        acc = fmaf(w1[oc*27 + q], win[q], acc);
      h1[((b*C1 + oc)*H1 + oy)*W1 + ox] = fmaxf(acc, 0.f);
    }
}

// ---------------- conv2: (64,32,112,112) -> relu -> (64,64,56,56), s=2 p=1 -----
__global__ __launch_bounds__(256) void conv2_kernel(const float* __restrict__ h1,
        const float* __restrict__ w2, const float* __restrict__ b2,
        float* __restrict__ h2) {
    int pos = blockIdx.x * 256 + threadIdx.x;        // 64*56*56 = 200704
    int b   = pos / (H2 * W2);
    int rem = pos - b * (H2 * W2);
    int oy  = rem / W2;
    int ox  = rem - oy * W2;
    int iy0 = oy * 2 - 1, ix0 = ox * 2 - 1;

    float acc[C2];
    #pragma unroll
    for (int oc = 0; oc < C2; ++oc) acc[oc] = b2[oc];

    for (int c = 0; c < C1; ++c) {                   // 32 input channels
      float win[9];
      #pragma unroll
      for (int dy = 0; dy < 3; ++dy)
        #pragma unroll
        for (int dx = 0; dx < 3; ++dx) {
          int iy = iy0 + dy, ix = ix0 + dx;
          bool ok = (iy >= 0) & (iy < H1) & (ix >= 0) & (ix < W1);
          win[dy*3 + dx] = ok ? h1[((b*C1 + c)*H1 + iy)*W1 + ix] : 0.f;
        }
      #pragma unroll
      for (int oc = 0; oc < C2; ++oc) {
        #pragma unroll
        for (int q = 0; q < 9; ++q)
          acc[oc] = fmaf(w2[(oc*C1 + c)*9 + q], win[q], acc[oc]);
      }
    }
    #pragma unroll
    for (int oc = 0; oc < C2; ++oc)
      h2[((b*C2 + oc)*H2 + oy)*W2 + ox] = fmaxf(acc[oc], 0.f);
}

// ---------------- global average pool: (64,64,56,56) -> feat (64,64) ----------
__global__ __launch_bounds__(256) void pool_kernel(const float* __restrict__ h2,
        float* __restrict__ feat) {
    int bc = blockIdx.x;                             // 0..4095 = b*64 + c
    const float* p = h2 + (size_t)bc * (H2 * W2);
    float s = 0.f;
    for (int i = threadIdx.x; i < H2 * W2; i += 256) s += p[i];
    #pragma unroll
    for (int off = 32; off; off >>= 1) s += __shfl_down(s, off);
    __shared__ float red[4];
    if ((threadIdx.x & 63) == 0) red[threadIdx.x >> 6] = s;
    __syncthreads();
    if (threadIdx.x == 0)
      feat[bc] = (red[0] + red[1] + red[2] + red[3]) * (1.f / (H2 * W2));
}

// ---------------- center: fc = feat - rowmean(feat) ---------------------------
__global__ __launch_bounds__(64) void center_kernel(const float* __restrict__ feat,
        float* __restrict__ fc) {
    __shared__ float fl[FEATN * FEATN];
    int t = threadIdx.x;                             // 64 threads; t = b
    for (int i = t; i < FEATN * FEATN; i += 64) fl[i] = feat[i];
    __syncthreads();
    float m = 0.f;
    for (int c = 0; c < FEATN; ++c) m += fl[t*FEATN + c];
    m *= (1.f / FEATN);
    for (int c = 0; c < FEATN; ++c) fc[t*FEATN + c] = fl[t*FEATN + c] - m;
}

// -------- mean_feat + cov_feat + all biases -> WRITES d_out -------------------
__global__ __launch_bounds__(256) void meancov_kernel(const float* __restrict__ feat,
        const float* __restrict__ fc,
        const float* __restrict__ wm, const float* __restrict__ bm,
        const float* __restrict__ wc, const float* __restrict__ bcv,
        const float* __restrict__ b3, float* __restrict__ out) {
    __shared__ float featT[FEATN * FEATN];           // [c][b]
    __shared__ float fcT[FEATN * FEATN];             // [c][b]
    int t = threadIdx.x;
    for (int i = t; i < FEATN * FEATN; i += 256) {
      int b = i >> 6, c = i & 63;
      featT[c*64 + b] = feat[i];
      fcT[c*64 + b]   = fc[i];
    }
    __syncthreads();

    int b = t & 63;
    int o = blockIdx.x * 4 + (t >> 6);               // 256 blocks * 4 = 1024
    float acc = bm[o] + bcv[o] + b3[o];
    #pragma unroll 8
    for (int c = 0; c < FEATN; ++c)
      acc = fmaf(featT[c*64 + b], wm[o*FEATN + c], acc);
    const float* wcrow = wc + (size_t)o * (FEATN * FEATN);
    for (int c1 = 0; c1 < FEATN; ++c1) {
      float a2 = 0.f;
      #pragma unroll 8
      for (int c2 = 0; c2 < FEATN; ++c2)
        a2 = fmaf(fcT[c2*64 + b], wcrow[c1*64 + c2], a2);
      acc = fmaf(fcT[c1*64 + b], a2, acc);
    }
    out[b * OUTN + o] = acc;
}

// -------- third-order term: C[b,o] += sum_ijk fc_i fc_j fc_k * w3[o,ijk] ------
// bf16 MFMA 16x16x32; A = fc3 on the fly (M=64 batches), B = w3^T cols.
// Grid: 16 N-blocks (64 cols) x 128 K-slices (32 (i,j) pairs each).
#define NBLKS 16
#define KSLICES 128
#define IJ_PER_BLOCK 32
__global__ __launch_bounds__(256) void third_kernel(const float* __restrict__ fc,
        const float* __restrict__ w3, float* __restrict__ out) {
    // fcL: row-major fc[b][k], XOR-swizzled per 8-float granule (conflict-free b128)
    // fcT: fcT[c][b] for the uniform-index s = fc_i*fc_j reads
    __shared__ float fcL[FEATN * FEATN];
    __shared__ float fcT[FEATN * FEATN];
    int t = threadIdx.x;
    for (int i = t; i < FEATN * FEATN; i += 256) {
      int b = i >> 6, k = i & 63;
      float v = fc[i];
      int g = k >> 3;
      fcL[b*64 + ((g ^ (b & 7)) << 3) + (k & 7)] = v;
      fcT[k*64 + b] = v;
    }
    __syncthreads();

    int nblk   = blockIdx.x & (NBLKS - 1);
    int kslice = blockIdx.x >> 4;
    int wave = t >> 6;
    int lane = t & 63;
    int l15  = lane & 15;
    int l4   = lane >> 4;                            // 0..3
    int ocol = nblk*64 + wave*16 + l15;              // output column (o)
    int ijbase = kslice * IJ_PER_BLOCK;

    f32x4 acc[4];
    #pragma unroll
    for (int m = 0; m < 4; ++m) acc[m] = (f32x4){0.f, 0.f, 0.f, 0.f};

    const float* w3col = w3 + (size_t)ocol * K3TOT;

    for (int ij = 0; ij < IJ_PER_BLOCK; ++ij) {
      int ijg = ijbase + ij;
      int i = ijg >> 6, j = ijg & 63;
      // s[m] = fc[b,i]*fc[b,j] for b = m*16 + l15  (uniform i,j -> conflict-free)
      float smul[4];
      #pragma unroll
      for (int m = 0; m < 4; ++m) {
        int bb = m*16 + l15;
        smul[m] = fcT[i*64 + bb] * fcT[j*64 + bb];
      }
      size_t kb = (size_t)ijg * 64;
      #pragma unroll
      for (int step = 0; step < 2; ++step) {
        int k3off = step*32 + l4*8;
        // B fragment: w3[ocol, kb + k3off .. +8)  (lane-contiguous 32B)
        const float* pw = w3col + kb + k3off;
        float4 b0 = *(const float4*)(pw);
        float4 b1 = *(const float4*)(pw + 4);
        bf16x8 bfrag;
        bfrag[0] = (__bf16)b0.x; bfrag[1] = (__bf16)b0.y;
        bfrag[2] = (__bf16)b0.z; bfrag[3] = (__bf16)b0.w;
        bfrag[4] = (__bf16)b1.x; bfrag[5] = (__bf16)b1.y;
        bfrag[6] = (__bf16)b1.z; bfrag[7] = (__bf16)b1.w;
        int gran = step*4 + l4;                      // 8-float granule index
        #pragma unroll
        for (int m = 0; m < 4; ++m) {
          int bb = m*16 + l15;
          const float* pf = &fcL[bb*64 + ((gran ^ (bb & 7)) << 3)];
          float4 a0 = *(const float4*)(pf);
          float4 a1 = *(const float4*)(pf + 4);
          float s = smul[m];
          bf16x8 afrag;
          afrag[0] = (__bf16)(a0.x * s); afrag[1] = (__bf16)(a0.y * s);
          afrag[2] = (__bf16)(a0.z * s); afrag[3] = (__bf16)(a0.w * s);
          afrag[4] = (__bf16)(a1.x * s); afrag[5] = (__bf16)(a1.y * s);
          afrag[6] = (__bf16)(a1.z * s); afrag[7] = (__bf16)(a1.w * s);
          acc[m] = __builtin_amdgcn_mfma_f32_16x16x32_bf16(afrag, bfrag, acc[m], 0, 0, 0);
        }
      }
    }
    // D layout (verified m89): col = lane&15, row = (lane>>4)*4 + reg
    #pragma unroll
    for (int m = 0; m < 4; ++m)
      #pragma unroll
      for (int r = 0; r < 4; ++r) {
        int row = m*16 + l4*4 + r;                   // batch
        atomicAdd(&out[row * OUTN + ocol], acc[m][r]);
      }
}

extern "C" void kernel_launch(void* const* d_in, const int* in_sizes, int n_in,
                              void* d_out, int out_size, void* d_ws, size_t ws_size,
                              hipStream_t stream) {
    const float* x   = (const float*)d_in[0];
    const float* w1  = (const float*)d_in[1];
    const float* b1  = (const float*)d_in[2];
    const float* w2  = (const float*)d_in[3];
    const float* b2  = (const float*)d_in[4];
    const float* wm  = (const float*)d_in[5];
    const float* bm  = (const float*)d_in[6];
    const float* wc  = (const float*)d_in[7];
    const float* bcv = (const float*)d_in[8];
    const float* w3  = (const float*)d_in[9];
    const float* b3  = (const float*)d_in[10];
    float* out = (float*)d_out;

    // workspace layout (floats): h1 | h2 | feat | fc   (total ~154.2 MB)
    float* ws   = (float*)d_ws;
    float* h1   = ws;                                // 64*32*112*112 = 25690112
    float* h2   = ws + 25690112;                     // 64*64*56*56   = 12845056
    float* feat = ws + 38535168;                     // 4096
    float* fcv  = ws + 38539264;                     // 4096

    conv1_kernel <<<3136, 256, 0, stream>>>(x, w1, b1, h1);
    conv2_kernel <<<784,  256, 0, stream>>>(h1, w2, b2, h2);
    pool_kernel  <<<4096, 256, 0, stream>>>(h2, feat);
    center_kernel<<<1,    64,  0, stream>>>(feat, fcv);
    meancov_kernel<<<256, 256, 0, stream>>>(feat, fcv, wm, bm, wc, bcv, b3, out);
    third_kernel <<<NBLKS * KSLICES, 256, 0, stream>>>(fcv, w3, out);
}